// Round 8
// baseline (3208.427 us; speedup 1.0000x reference)
//
#include <hip/hip_runtime.h>

// SO3SelfInteraction: y[a,k,f] = sum_e Wcg[e] * x[a,i1[e],f] * x[a,i2[e],f]
// LMAX=2 -> S=9, N_ATOMS=32000, N_FEAT=128.
//
// R7: fused PERSISTENT kernel at capped concurrency.
//  - grid = 1000 blocks (<=4 blocks/CU resident -> same healthy concurrency
//    as R3; R5 proved 8 blocks/CU thrashes MALL: FETCH 72->227MB).
//  - each block builds merged W[45][12] in LDS once (<=2 commutative fp
//    atomics per cell -> bitwise deterministic), then grid-strides 4 chunks.
//  - weights consumed via uniform-address ds_read_b128 (broadcast, no
//    conflict, separate LDS pipe -> hides under memory wall).
//  - removes the prep kernel dispatch + graph-dependency gap (~5us).

#define S9 9
#define NFEAT 128
#define THREADS 256
#define NPAIR 45
#define WSTRIDE 12   // padded floats per pair row (48 B)
#define GRID 1000

typedef float f4 __attribute__((ext_vector_type(4)));

__global__ __launch_bounds__(THREADS) void so3_fused_kernel(
        const float* __restrict__ x,
        const float* __restrict__ weight,
        const float* __restrict__ cg_vals,
        const int* __restrict__ idx_1,
        const int* __restrict__ idx_2,
        const int* __restrict__ idx_out,
        const int* __restrict__ widx_1,
        const int* __restrict__ widx_2,
        int nnz,
        float* __restrict__ y,
        int total_chunks) {
    __shared__ __align__(16) float Wlds[NPAIR * WSTRIDE];

    const int tid = threadIdx.x;

    // ---- per-block prep: build merged weight table in LDS ----
    #pragma unroll
    for (int i = tid; i < NPAIR * WSTRIDE; i += THREADS) Wlds[i] = 0.f;
    __syncthreads();

    for (int e = tid; e < nnz; e += THREADS) {
        const int i = idx_1[e];
        const int j = idx_2[e];
        const int k = idx_out[e];
        const float w = weight[widx_1[e] * 3 + widx_2[e]] * cg_vals[e];
        const int a = min(i, j);
        const int b = max(i, j);
        const int p = a * 9 - a * (a - 1) / 2 + (b - a);
        // <=2 adds per cell ((i,j),(j,i)); fp add commutative -> deterministic
        atomicAdd(&Wlds[p * WSTRIDE + k], w);
    }
    __syncthreads();

    static constexpr int PA[NPAIR] = {
        0,0,0,0,0,0,0,0,0, 1,1,1,1,1,1,1,1, 2,2,2,2,2,2,2,
        3,3,3,3,3,3, 4,4,4,4,4, 5,5,5,5, 6,6,6, 7,7, 8};
    static constexpr int PB[NPAIR] = {
        0,1,2,3,4,5,6,7,8, 1,2,3,4,5,6,7,8, 2,3,4,5,6,7,8,
        3,4,5,6,7,8, 4,5,6,7,8, 5,6,7,8, 6,7,8, 7,8, 8};

    const int stride = GRID * THREADS;                   // 256,000 threads
    const int g = blockIdx.x * THREADS + tid;

    for (int chunk = g; chunk < total_chunks; chunk += stride) {
        const int atom = chunk >> 5;
        const int c4   = chunk & 31;
        const size_t base = (size_t)atom * (S9 * NFEAT) + (size_t)c4 * 4;

        f4 xv[S9];
        #pragma unroll
        for (int s = 0; s < S9; ++s)
            xv[s] = *(const f4*)(x + base + (size_t)s * NFEAT);

        f4 acc[S9];
        #pragma unroll
        for (int k = 0; k < S9; ++k) acc[k] = (f4)0.f;

        #pragma unroll
        for (int p = 0; p < NPAIR; ++p) {
            // uniform-address LDS reads: broadcast, conflict-free
            const f4 wA = *(const f4*)(&Wlds[p * WSTRIDE]);      // k = 0..3
            const f4 wB = *(const f4*)(&Wlds[p * WSTRIDE + 4]);  // k = 4..7
            const f4 wC = *(const f4*)(&Wlds[p * WSTRIDE + 8]);  // k = 8
            const f4 prod = xv[PA[p]] * xv[PB[p]];
            acc[0] = acc[0] + wA[0] * prod;
            acc[1] = acc[1] + wA[1] * prod;
            acc[2] = acc[2] + wA[2] * prod;
            acc[3] = acc[3] + wA[3] * prod;
            acc[4] = acc[4] + wB[0] * prod;
            acc[5] = acc[5] + wB[1] * prod;
            acc[6] = acc[6] + wB[2] * prod;
            acc[7] = acc[7] + wB[3] * prod;
            acc[8] = acc[8] + wC[0] * prod;
        }

        #pragma unroll
        for (int k = 0; k < S9; ++k)
            *(f4*)(y + base + (size_t)k * NFEAT) = acc[k];
    }
}

extern "C" void kernel_launch(void* const* d_in, const int* in_sizes, int n_in,
                              void* d_out, int out_size, void* d_ws, size_t ws_size,
                              hipStream_t stream) {
    const float* x       = (const float*)d_in[0];
    const float* weight  = (const float*)d_in[1];
    const float* cg_vals = (const float*)d_in[2];
    const int* idx_1     = (const int*)d_in[3];
    const int* idx_2     = (const int*)d_in[4];
    const int* idx_out   = (const int*)d_in[5];
    const int* widx_1    = (const int*)d_in[6];
    const int* widx_2    = (const int*)d_in[7];
    float* y             = (float*)d_out;

    const int nnz     = in_sizes[2];
    const int n_atoms = in_sizes[0] / (S9 * NFEAT);       // 32000

    const int total_chunks = n_atoms * 32;                // 1,024,000
    so3_fused_kernel<<<GRID, THREADS, 0, stream>>>(
        x, weight, cg_vals, idx_1, idx_2, idx_out, widx_1, widx_2, nnz,
        y, total_chunks);
}

// Round 9
// 57.060 us; speedup vs baseline: 56.2287x; 56.2287x over previous
//
#include <hip/hip_runtime.h>

// SO3SelfInteraction: y[a,k,f] = sum_e Wcg[e] * x[a,i1[e],f] * x[a,i2[e],f]
// LMAX=2 -> S=9, N_ATOMS=32000, N_FEAT=128.
//
// R8: fused single-dispatch kernel, NO loop (one chunk per thread, grid=4000)
// so the R7 LICM->spill disaster cannot occur (R5's no-loop body was VGPR 32).
// Occupancy capped at 4 blocks/CU via 36 KB DYNAMIC LDS padding -- the single
// variable separating R5's MALL-thrash (8 blocks/CU, FETCH 72->227 MB) from
// R1/R3's healthy traffic (4 blocks/CU, 72/144 MB).
//  - per-block prep: merged pair-major W[45][12] in LDS, <=2 commutative fp
//    atomics per cell -> bitwise deterministic.
//  - weights via uniform-address ds_read_b128 (broadcast, conflict-free).
//  - register-resident xv/acc, straight-line 45-pair unroll, plain f4 stores.

#define S9 9
#define NFEAT 128
#define THREADS 256
#define NPAIR 45
#define WSTRIDE 12            // padded floats per pair row (48 B)
#define LDS_BYTES (36 * 1024) // dynamic LDS: caps residency at 4 blocks/CU

typedef float f4 __attribute__((ext_vector_type(4)));

__global__ __launch_bounds__(THREADS) void so3_fused_kernel(
        const float* __restrict__ x,
        const float* __restrict__ weight,
        const float* __restrict__ cg_vals,
        const int* __restrict__ idx_1,
        const int* __restrict__ idx_2,
        const int* __restrict__ idx_out,
        const int* __restrict__ widx_1,
        const int* __restrict__ widx_2,
        int nnz,
        float* __restrict__ y) {
    extern __shared__ __align__(16) float Wlds[];   // 36 KB allocated, 540 used

    const int tid = threadIdx.x;

    // ---- per-block prep: build merged weight table in LDS ----
    #pragma unroll
    for (int i = tid; i < NPAIR * WSTRIDE; i += THREADS) Wlds[i] = 0.f;
    __syncthreads();

    for (int e = tid; e < nnz; e += THREADS) {
        const int i = idx_1[e];
        const int j = idx_2[e];
        const int k = idx_out[e];
        const float w = weight[widx_1[e] * 3 + widx_2[e]] * cg_vals[e];
        const int a = min(i, j);
        const int b = max(i, j);
        const int p = a * 9 - a * (a - 1) / 2 + (b - a);
        // <=2 adds per cell ((i,j),(j,i)); fp add commutative -> deterministic
        atomicAdd(&Wlds[p * WSTRIDE + k], w);
    }
    __syncthreads();

    // ---- main compute: one (atom, f4-column) chunk per thread ----
    static constexpr int PA[NPAIR] = {
        0,0,0,0,0,0,0,0,0, 1,1,1,1,1,1,1,1, 2,2,2,2,2,2,2,
        3,3,3,3,3,3, 4,4,4,4,4, 5,5,5,5, 6,6,6, 7,7, 8};
    static constexpr int PB[NPAIR] = {
        0,1,2,3,4,5,6,7,8, 1,2,3,4,5,6,7,8, 2,3,4,5,6,7,8,
        3,4,5,6,7,8, 4,5,6,7,8, 5,6,7,8, 6,7,8, 7,8, 8};

    const int gid  = blockIdx.x * THREADS + tid;
    const int atom = gid >> 5;
    const int c4   = gid & 31;
    const size_t base = (size_t)atom * (S9 * NFEAT) + (size_t)c4 * 4;

    f4 xv[S9];
    #pragma unroll
    for (int s = 0; s < S9; ++s)
        xv[s] = *(const f4*)(x + base + (size_t)s * NFEAT);

    f4 acc[S9];
    #pragma unroll
    for (int k = 0; k < S9; ++k) acc[k] = (f4)0.f;

    #pragma unroll
    for (int p = 0; p < NPAIR; ++p) {
        // uniform-address LDS reads: broadcast, conflict-free
        const f4 wA = *(const f4*)(&Wlds[p * WSTRIDE]);      // k = 0..3
        const f4 wB = *(const f4*)(&Wlds[p * WSTRIDE + 4]);  // k = 4..7
        const f4 wC = *(const f4*)(&Wlds[p * WSTRIDE + 8]);  // k = 8 (+pad)
        const f4 prod = xv[PA[p]] * xv[PB[p]];
        acc[0] = acc[0] + wA[0] * prod;
        acc[1] = acc[1] + wA[1] * prod;
        acc[2] = acc[2] + wA[2] * prod;
        acc[3] = acc[3] + wA[3] * prod;
        acc[4] = acc[4] + wB[0] * prod;
        acc[5] = acc[5] + wB[1] * prod;
        acc[6] = acc[6] + wB[2] * prod;
        acc[7] = acc[7] + wB[3] * prod;
        acc[8] = acc[8] + wC[0] * prod;
    }

    #pragma unroll
    for (int k = 0; k < S9; ++k)
        *(f4*)(y + base + (size_t)k * NFEAT) = acc[k];
}

extern "C" void kernel_launch(void* const* d_in, const int* in_sizes, int n_in,
                              void* d_out, int out_size, void* d_ws, size_t ws_size,
                              hipStream_t stream) {
    const float* x       = (const float*)d_in[0];
    const float* weight  = (const float*)d_in[1];
    const float* cg_vals = (const float*)d_in[2];
    const int* idx_1     = (const int*)d_in[3];
    const int* idx_2     = (const int*)d_in[4];
    const int* idx_out   = (const int*)d_in[5];
    const int* widx_1    = (const int*)d_in[6];
    const int* widx_2    = (const int*)d_in[7];
    float* y             = (float*)d_out;

    const int nnz     = in_sizes[2];
    const int n_atoms = in_sizes[0] / (S9 * NFEAT);       // 32000

    const int total = n_atoms * 32;                        // 1,024,000 chunks
    so3_fused_kernel<<<total / THREADS, THREADS, LDS_BYTES, stream>>>(
        x, weight, cg_vals, idx_1, idx_2, idx_out, widx_1, widx_2, nnz, y);
}